// Round 2
// baseline (384.670 us; speedup 1.0000x reference)
//
#include <hip/hip_runtime.h>

#define B_ 64
#define TX_ 2048
#define DA_ 256
#define DS_ 256
#define H_ 50
#define HP_ 53  // padded LDS row stride; gcd(53,32)=1 -> conflict-free column access

// ---------------------------------------------------------------------------
// prep: grid B_ x 256. Zero the output accumulator and compute the per-batch
// constant c[b][h] = b1[h] + sum_k s[b,k]*W1[DA_+k,h]  (s-part of the dense).
// ---------------------------------------------------------------------------
__global__ __launch_bounds__(256) void prep_kernel(
    const float* __restrict__ s, const float* __restrict__ W1,
    const float* __restrict__ b1, float* __restrict__ c_ws,
    float* __restrict__ out)
{
  const int b = blockIdx.x;
  const int tid = threadIdx.x;
  if (tid < DA_) out[b * DA_ + tid] = 0.0f;

  const int h4 = tid >> 2, kq = tid & 3;  // thread quad covers one h, k in 4 chunks
  float cp = 0.0f;
  if (h4 < H_) {
    const float* srow = s + b * DS_;
    #pragma unroll 8
    for (int k = kq * 64; k < kq * 64 + 64; ++k)
      cp += srow[k] * W1[(size_t)(DA_ + k) * H_ + h4];
  }
  cp += __shfl_down(cp, 1);
  cp += __shfl_down(cp, 2);
  if (h4 < H_ && kq == 0) c_ws[b * H_ + h4] = cp + b1[h4];
}

// ---------------------------------------------------------------------------
// e_kernel: grid 2048 x 256. Block = 64 rows; wave = k-slice (64 of 256 a-dims)
// so W1 addresses stay wave-uniform (scalar loads). 8192 waves total for
// latency hiding. Partials reduced across the 4 waves via LDS f32 atomics.
// ---------------------------------------------------------------------------
__global__ __launch_bounds__(256) void e_kernel(
    const float* __restrict__ a, const float* __restrict__ W1,
    const float* __restrict__ c_ws, const float* __restrict__ W2,
    const float* __restrict__ b2, float* __restrict__ w_exp)
{
  __shared__ float red[64][HP_];
  __shared__ float c_sh[H_], w2_sh[H_];
  const int tid = threadIdx.x;
  const int lane = tid & 63;  // row within block
  const int ks = tid >> 6;    // k-slice = wave index
  const int blk = blockIdx.x;
  const int row0 = blk * 64;
  const int b = blk >> 5;     // 32 blocks per batch

  for (int i = tid; i < 64 * HP_; i += 256) (&red[0][0])[i] = 0.0f;
  if (tid < H_) { c_sh[tid] = c_ws[b * H_ + tid]; w2_sh[tid] = W2[tid]; }
  __syncthreads();

  float acc[H_];
  #pragma unroll
  for (int h = 0; h < H_; ++h) acc[h] = 0.0f;

  const float* arow = a + (size_t)(row0 + lane) * DA_ + ks * 64;
  const float* w1s = W1 + (size_t)(ks * 64) * H_;  // wave-uniform base
  for (int j = 0; j < 16; ++j) {
    const float4 av = *(const float4*)(arow + j * 4);
    const float* wk = w1s + (size_t)(j * 4) * H_;  // 200 contiguous floats, uniform
    #pragma unroll
    for (int h = 0; h < H_; ++h)
      acc[h] += av.x * wk[h] + av.y * wk[H_ + h]
              + av.z * wk[2 * H_ + h] + av.w * wk[3 * H_ + h];
  }

  #pragma unroll
  for (int h = 0; h < H_; ++h) atomicAdd(&red[lane][h], acc[h]);
  __syncthreads();

  if (ks == 0) {
    float e = b2[0];
    #pragma unroll
    for (int h = 0; h < H_; ++h)
      e += fmaxf(red[lane][h] + c_sh[h], 0.0f) * w2_sh[h];
    // e in [-1,1] after tanh -> exp safe without max subtraction
    w_exp[row0 + lane] = __expf(tanhf(e));
  }
}

// ---------------------------------------------------------------------------
// ctx_kernel: grid 512 (64 b x 8 t-chunks) x 256. Redundant per-block softmax
// denominator (8 KB re-read), weighted partial sum of a, atomic accumulate.
// ---------------------------------------------------------------------------
__global__ __launch_bounds__(256) void ctx_kernel(
    const float* __restrict__ a, const float* __restrict__ w_exp,
    float* __restrict__ out)
{
  __shared__ float wsm[TX_];
  __shared__ float red[256];
  const int tid = threadIdx.x;
  const int blk = blockIdx.x;
  const int b = blk >> 3;
  const int ch = blk & 7;

  const float* wb = w_exp + b * TX_;
  float local = 0.0f;
  #pragma unroll
  for (int i = 0; i < TX_ / 256; ++i) {
    const float v = wb[tid + i * 256];
    wsm[tid + i * 256] = v;
    local += v;
  }
  red[tid] = local;
  __syncthreads();
  for (int step = 128; step > 0; step >>= 1) {
    if (tid < step) red[tid] += red[tid + step];
    __syncthreads();
  }
  const float invS = 1.0f / red[0];

  const int d4 = (tid & 63) * 4;
  const int trow = tid >> 6;
  const int t0 = ch * 256;
  float4 acc = {0.0f, 0.0f, 0.0f, 0.0f};
  const float* ab = a + ((size_t)b * TX_ + t0 + trow) * DA_ + d4;
  #pragma unroll 4
  for (int i = 0; i < 64; ++i) {
    const float4 av = *(const float4*)(ab + (size_t)(4 * i) * DA_);
    const float wv = wsm[t0 + trow + 4 * i];
    acc.x += wv * av.x;
    acc.y += wv * av.y;
    acc.z += wv * av.z;
    acc.w += wv * av.w;
  }
  float* o = out + b * DA_ + d4;
  atomicAdd(o + 0, acc.x * invS);
  atomicAdd(o + 1, acc.y * invS);
  atomicAdd(o + 2, acc.z * invS);
  atomicAdd(o + 3, acc.w * invS);
}

extern "C" void kernel_launch(void* const* d_in, const int* in_sizes, int n_in,
                              void* d_out, int out_size, void* d_ws, size_t ws_size,
                              hipStream_t stream) {
  const float* a  = (const float*)d_in[0];
  const float* s  = (const float*)d_in[1];
  const float* W1 = (const float*)d_in[2];
  const float* b1 = (const float*)d_in[3];
  const float* W2 = (const float*)d_in[4];
  const float* b2 = (const float*)d_in[5];
  float* out = (float*)d_out;

  float* c_ws  = (float*)d_ws;               // B_*H_ = 3200 floats
  float* w_exp = (float*)d_ws + 4096;        // B_*TX_ = 131072 floats

  prep_kernel<<<dim3(B_), dim3(256), 0, stream>>>(s, W1, b1, c_ws, out);
  e_kernel<<<dim3(2048), dim3(256), 0, stream>>>(a, W1, c_ws, W2, b2, w_exp);
  ctx_kernel<<<dim3(512), dim3(256), 0, stream>>>(a, w_exp, out);
}

// Round 3
// 219.676 us; speedup vs baseline: 1.7511x; 1.7511x over previous
//
#include <hip/hip_runtime.h>

#define B_ 64
#define TX_ 2048
#define DA_ 256
#define DS_ 256
#define H_ 50
#define HP_ 53  // padded LDS row stride; gcd(53,32)=1 -> conflict-free column access

// ---------------------------------------------------------------------------
// prep: grid B_ x 256. Zero the output accumulator and compute the per-batch
// constant c[b][h] = b1[h] + sum_k s[b,k]*W1[DA_+k,h]  (s-part of the dense).
// ---------------------------------------------------------------------------
__global__ __launch_bounds__(256) void prep_kernel(
    const float* __restrict__ s, const float* __restrict__ W1,
    const float* __restrict__ b1, float* __restrict__ c_ws,
    float* __restrict__ out)
{
  const int b = blockIdx.x;
  const int tid = threadIdx.x;
  if (tid < DA_) out[b * DA_ + tid] = 0.0f;

  const int h4 = tid >> 2, kq = tid & 3;  // thread quad covers one h, k in 4 chunks
  float cp = 0.0f;
  if (h4 < H_) {
    const float* srow = s + b * DS_;
    #pragma unroll 8
    for (int k = kq * 64; k < kq * 64 + 64; ++k)
      cp += srow[k] * W1[(size_t)(DA_ + k) * H_ + h4];
  }
  cp += __shfl_down(cp, 1);
  cp += __shfl_down(cp, 2);
  if (h4 < H_ && kq == 0) c_ws[b * H_ + h4] = cp + b1[h4];
}

// ---------------------------------------------------------------------------
// e_kernel: grid 2048 x 256. Block = 64 rows; wave = k-slice (64 of 256 a-dims).
// ks is forced into an SGPR via readfirstlane so the W1 addressing is provably
// wave-uniform -> s_load chains (R2 regression: tid-derived ks made the
// compiler emit 3200 per-lane vector loads for W1; SGPR_Count 112->32).
// 8192 waves total (32/CU) hide the s_load latency that capped R1 at 25%.
// Partials reduced across the 4 waves via LDS f32 atomics.
// ---------------------------------------------------------------------------
__global__ __launch_bounds__(256) void e_kernel(
    const float* __restrict__ a, const float* __restrict__ W1,
    const float* __restrict__ c_ws, const float* __restrict__ W2,
    const float* __restrict__ b2, float* __restrict__ w_exp)
{
  __shared__ float red[64][HP_];
  __shared__ float c_sh[H_], w2_sh[H_];
  const int tid = threadIdx.x;
  const int lane = tid & 63;  // row within block
  // wave-uniform k-slice index, pinned to an SGPR:
  const int ks = __builtin_amdgcn_readfirstlane(tid >> 6);
  const int blk = blockIdx.x;
  const int row0 = blk * 64;
  const int b = blk >> 5;     // 32 blocks per batch

  for (int i = tid; i < 64 * HP_; i += 256) (&red[0][0])[i] = 0.0f;
  if (tid < H_) { c_sh[tid] = c_ws[b * H_ + tid]; w2_sh[tid] = W2[tid]; }
  __syncthreads();

  float acc[H_];
  #pragma unroll
  for (int h = 0; h < H_; ++h) acc[h] = 0.0f;

  const float* arow = a + (size_t)(row0 + lane) * DA_ + ks * 64;
  const float* w1s = W1 + (size_t)(ks * 64) * H_;  // SGPR base -> scalar loads
  for (int j = 0; j < 16; ++j) {
    const float4 av = *(const float4*)(arow + j * 4);
    const float* wk = w1s + (size_t)(j * 4) * H_;  // 200 contiguous floats, uniform
    #pragma unroll
    for (int h = 0; h < H_; ++h)
      acc[h] += av.x * wk[h] + av.y * wk[H_ + h]
              + av.z * wk[2 * H_ + h] + av.w * wk[3 * H_ + h];
  }

  #pragma unroll
  for (int h = 0; h < H_; ++h) atomicAdd(&red[lane][h], acc[h]);
  __syncthreads();

  if (ks == 0) {
    float e = b2[0];
    #pragma unroll
    for (int h = 0; h < H_; ++h)
      e += fmaxf(red[lane][h] + c_sh[h], 0.0f) * w2_sh[h];
    // e in [-1,1] after tanh -> exp safe without max subtraction
    w_exp[row0 + lane] = __expf(tanhf(e));
  }
}

// ---------------------------------------------------------------------------
// ctx_kernel: grid 512 (64 b x 8 t-chunks) x 256. Redundant per-block softmax
// denominator (8 KB re-read), weighted partial sum of a, atomic accumulate.
// ---------------------------------------------------------------------------
__global__ __launch_bounds__(256) void ctx_kernel(
    const float* __restrict__ a, const float* __restrict__ w_exp,
    float* __restrict__ out)
{
  __shared__ float wsm[TX_];
  __shared__ float red[256];
  const int tid = threadIdx.x;
  const int blk = blockIdx.x;
  const int b = blk >> 3;
  const int ch = blk & 7;

  const float* wb = w_exp + b * TX_;
  float local = 0.0f;
  #pragma unroll
  for (int i = 0; i < TX_ / 256; ++i) {
    const float v = wb[tid + i * 256];
    wsm[tid + i * 256] = v;
    local += v;
  }
  red[tid] = local;
  __syncthreads();
  for (int step = 128; step > 0; step >>= 1) {
    if (tid < step) red[tid] += red[tid + step];
    __syncthreads();
  }
  const float invS = 1.0f / red[0];

  const int d4 = (tid & 63) * 4;
  const int trow = tid >> 6;
  const int t0 = ch * 256;
  float4 acc = {0.0f, 0.0f, 0.0f, 0.0f};
  const float* ab = a + ((size_t)b * TX_ + t0 + trow) * DA_ + d4;
  #pragma unroll 4
  for (int i = 0; i < 64; ++i) {
    const float4 av = *(const float4*)(ab + (size_t)(4 * i) * DA_);
    const float wv = wsm[t0 + trow + 4 * i];
    acc.x += wv * av.x;
    acc.y += wv * av.y;
    acc.z += wv * av.z;
    acc.w += wv * av.w;
  }
  float* o = out + b * DA_ + d4;
  atomicAdd(o + 0, acc.x * invS);
  atomicAdd(o + 1, acc.y * invS);
  atomicAdd(o + 2, acc.z * invS);
  atomicAdd(o + 3, acc.w * invS);
}

extern "C" void kernel_launch(void* const* d_in, const int* in_sizes, int n_in,
                              void* d_out, int out_size, void* d_ws, size_t ws_size,
                              hipStream_t stream) {
  const float* a  = (const float*)d_in[0];
  const float* s  = (const float*)d_in[1];
  const float* W1 = (const float*)d_in[2];
  const float* b1 = (const float*)d_in[3];
  const float* W2 = (const float*)d_in[4];
  const float* b2 = (const float*)d_in[5];
  float* out = (float*)d_out;

  float* c_ws  = (float*)d_ws;               // B_*H_ = 3200 floats
  float* w_exp = (float*)d_ws + 4096;        // B_*TX_ = 131072 floats

  prep_kernel<<<dim3(B_), dim3(256), 0, stream>>>(s, W1, b1, c_ws, out);
  e_kernel<<<dim3(2048), dim3(256), 0, stream>>>(a, W1, c_ws, W2, b2, w_exp);
  ctx_kernel<<<dim3(512), dim3(256), 0, stream>>>(a, w_exp, out);
}

// Round 4
// 66.211 us; speedup vs baseline: 5.8097x; 3.3178x over previous
//
#include <hip/hip_runtime.h>

#define B_ 64
#define TX_ 2048
#define DA_ 256
#define DS_ 256
#define H_ 50

typedef __attribute__((ext_vector_type(4))) float f32x4;
typedef __attribute__((ext_vector_type(8))) short short8;

// bf16 RNE helpers (bit math; matches jax RNE closely enough)
__device__ __forceinline__ unsigned short f2bf(float x) {
  unsigned int u = __builtin_bit_cast(unsigned int, x);
  u += 0x7FFFu + ((u >> 16) & 1u);
  return (unsigned short)(u >> 16);
}
__device__ __forceinline__ float bf2f(unsigned short h) {
  unsigned int u = ((unsigned int)h) << 16;
  return __builtin_bit_cast(float, u);
}

// ws layout (float units): num[16384] @0 | den[64] @16384 | c_ws[64*64] @16448
// | w2p[64] @20544 | wsB (32768 ushort = 64KB) @float 20608
#define WS_NUM 0
#define WS_DEN 16384
#define WS_C   16448
#define WS_W2  20544
#define WS_B   20608

// ---------------------------------------------------------------------------
// prep: grid 64 x 256. Zero num/den; c[b][h] = b1[h] + s@W1s (padded to 64);
// w2 padded; W1a split hi/lo into MFMA B-fragment order:
// wsB[((c*2+term)*4+nt)*512 + lane*8 + j], k = c*32+(lane>>4)*8+j, n = nt*16+(lane&15)
// ---------------------------------------------------------------------------
__global__ __launch_bounds__(256) void prep_kernel(
    const float* __restrict__ s, const float* __restrict__ W1,
    const float* __restrict__ b1, const float* __restrict__ W2,
    float* __restrict__ ws)
{
  const int b = blockIdx.x;
  const int t = threadIdx.x;
  float* num = ws + WS_NUM;
  float* den = ws + WS_DEN;
  float* cws = ws + WS_C;
  float* w2p = ws + WS_W2;
  unsigned short* wsB = (unsigned short*)(ws + WS_B);

  num[b * 256 + t] = 0.0f;
  if (t == 0) den[b] = 0.0f;

  // c[b][h], padded to 64
  {
    const int h4 = t >> 2, kq = t & 3;
    float cp = 0.0f;
    if (h4 < H_) {
      const float* srow = s + b * DS_;
      #pragma unroll 8
      for (int k = kq * 64; k < kq * 64 + 64; ++k)
        cp += srow[k] * W1[(size_t)(DA_ + k) * H_ + h4];
    }
    cp += __shfl_down(cp, 1);
    cp += __shfl_down(cp, 2);
    if (kq == 0) cws[b * 64 + h4] = (h4 < H_) ? (cp + b1[h4]) : 0.0f;
  }
  if (b == 0 && t < 64) w2p[t] = (t < H_) ? W2[t] : 0.0f;

  // B-fragments: 32768 values, 2 per thread
  #pragma unroll
  for (int ii = 0; ii < 2; ++ii) {
    const int idx = (b * 256 + t) * 2 + ii;
    const int j = idx & 7;
    const int l = (idx >> 3) & 63;
    const int nt = (idx >> 9) & 3;
    const int term = (idx >> 11) & 1;
    const int c = idx >> 12;
    const int k = c * 32 + (l >> 4) * 8 + j;
    const int n = nt * 16 + (l & 15);
    const float wv = (n < H_) ? W1[(size_t)k * H_ + n] : 0.0f;
    const unsigned short hi = f2bf(wv);
    const unsigned short val = term == 0 ? hi : f2bf(wv - bf2f(hi));
    wsB[((size_t)((c * 2 + term) * 4 + nt)) * 512 + l * 8 + j] = val;
  }
}

// ---------------------------------------------------------------------------
// fused: grid 2048 x 256 (4 waves). Block = 64 rows of one batch.
// Pass 1: stage a-tile (8 chunks x 64rows x 32k, XOR-swizzled) via
// global_load_lds, split-bf16 MFMA -> h -> e -> w=exp(tanh(e)).
// Pass 2: context partial sums straight from the LDS-resident tile.
// ---------------------------------------------------------------------------
__global__ __launch_bounds__(256) void fused_kernel(
    const float* __restrict__ a, const float* __restrict__ ws_f,
    const float* __restrict__ b2, float* __restrict__ num,
    float* __restrict__ den)
{
  __shared__ float tile[16384];  // 64KB: chunk c at floats [c*2048, +2048)
  __shared__ float w_sh[64];
  __shared__ float c_sh[64], w2_sh[64];

  const int t = threadIdx.x;
  const int l = t & 63;
  const int w = __builtin_amdgcn_readfirstlane(t >> 6);
  const int blk = blockIdx.x;
  const int b = blk >> 5;          // 32 blocks per batch
  const long R0 = (long)blk * 64;  // first global row

  const float* cws = ws_f + WS_C;
  const float* w2p = ws_f + WS_W2;
  const unsigned short* wsB = (const unsigned short*)(ws_f + WS_B);

  if (t < 64) { c_sh[t] = cws[b * 64 + t]; w2_sh[t] = w2p[t]; }

  // Stage chunk c: 2 global_load_lds(16B) per thread. LDS dest is linear
  // (wave-uniform base + lane*16); global source pre-swizzled so LDS holds
  // a[row][byte ^ ((row&7)<<4)] -> conflict-free ds_read later.
  #define STAGE(c)                                                             \
    {                                                                          \
      _Pragma("unroll")                                                        \
      for (int i = 0; i < 2; ++i) {                                            \
        const int slot = w * 2 + i;                                            \
        const int row = slot * 8 + (l >> 3);                                   \
        const long gbyte = (R0 + row) * 1024 + (c) * 128 +                     \
                           (((l & 7) ^ ((l >> 3) & 7)) * 16);                  \
        __builtin_amdgcn_global_load_lds(                                      \
            (const __attribute__((address_space(1))) void*)((const char*)a +   \
                                                            gbyte),            \
            (__attribute__((address_space(3))) void*)&tile[(c)*2048 +          \
                                                           slot * 256],        \
            16, 0, 0);                                                         \
      }                                                                        \
    }

  STAGE(0);
  STAGE(1);

  f32x4 acc[4];
  #pragma unroll
  for (int nt = 0; nt < 4; ++nt) acc[nt] = (f32x4){0.f, 0.f, 0.f, 0.f};

  #pragma unroll
  for (int c = 0; c < 8; ++c) {
    if (c + 2 < 8) STAGE(c + 2);
    // Counted wait: own chunk-c stage calls retired (leave c+1/c+2 in flight),
    // then barrier => chunk c fully in LDS for all waves.
    if (c < 6)      asm volatile("s_waitcnt vmcnt(4)" ::: "memory");
    else if (c == 6) asm volatile("s_waitcnt vmcnt(2)" ::: "memory");
    else             asm volatile("s_waitcnt vmcnt(0)" ::: "memory");
    __builtin_amdgcn_sched_barrier(0);
    __builtin_amdgcn_s_barrier();

    // B-fragments (L2-resident ws): hi and lo, 4 n-tiles
    const short8* Bp = (const short8*)(wsB + (size_t)c * 4096);
    short8 Bh[4], Bl[4];
    #pragma unroll
    for (int nt = 0; nt < 4; ++nt) {
      Bh[nt] = Bp[nt * 64 + l];
      Bl[nt] = Bp[(4 + nt) * 64 + l];
    }

    // A-fragment: row = w*16 + (l&15), k = (l>>4)*8 + j
    const int row = w * 16 + (l & 15);
    const int mask = (l & 15 & 7) << 4;
    const int obase = (l >> 4) * 32;
    const char* tb = (const char*)tile + (size_t)c * 8192 + row * 128;
    const float4 v0 = *(const float4*)(tb + (obase ^ mask));
    const float4 v1 = *(const float4*)(tb + ((obase + 16) ^ mask));
    float av[8] = {v0.x, v0.y, v0.z, v0.w, v1.x, v1.y, v1.z, v1.w};
    short8 Ah, Al;
    #pragma unroll
    for (int j = 0; j < 8; ++j) {
      const unsigned short hi = f2bf(av[j]);
      Ah[j] = (short)hi;
      Al[j] = (short)f2bf(av[j] - bf2f(hi));
    }

    #pragma unroll
    for (int nt = 0; nt < 4; ++nt) {
      acc[nt] = __builtin_amdgcn_mfma_f32_16x16x32_bf16(Ah, Bh[nt], acc[nt], 0, 0, 0);
      acc[nt] = __builtin_amdgcn_mfma_f32_16x16x32_bf16(Ah, Bl[nt], acc[nt], 0, 0, 0);
      acc[nt] = __builtin_amdgcn_mfma_f32_16x16x32_bf16(Al, Bh[nt], acc[nt], 0, 0, 0);
    }
  }

  // Epilogue: h -> e -> w. C layout: n = nt*16 + (l&15), row = w*16+(l>>4)*4+r
  const float b2v = b2[0];
  #pragma unroll
  for (int r = 0; r < 4; ++r) {
    float e = 0.0f;
    #pragma unroll
    for (int nt = 0; nt < 4; ++nt) {
      const int n = nt * 16 + (l & 15);
      e += fmaxf(acc[nt][r] + c_sh[n], 0.0f) * w2_sh[n];
    }
    e += __shfl_xor(e, 1);
    e += __shfl_xor(e, 2);
    e += __shfl_xor(e, 4);
    e += __shfl_xor(e, 8);
    if ((l & 15) == 0)
      w_sh[w * 16 + (l >> 4) * 4 + r] = __expf(tanhf(e + b2v));
  }
  __syncthreads();

  // Denominator partial (wave 0)
  if (t < 64) {
    float v = w_sh[t];
    #pragma unroll
    for (int off = 32; off > 0; off >>= 1) v += __shfl_xor(v, off);
    if (t == 0) atomicAdd(&den[b], v);
  }

  // Pass 2: context partials from the LDS tile. Thread t owns column t:
  // chunk = t>>5, col-in-chunk = t&31.
  {
    const int cc = t >> 5, col = t & 31;
    const char* tb = (const char*)tile + (size_t)cc * 8192;
    float sum = 0.0f;
    #pragma unroll 8
    for (int r = 0; r < 64; ++r) {
      const float av = *(const float*)(tb + r * 128 + ((col * 4) ^ ((r & 7) << 4)));
      sum += w_sh[r] * av;
    }
    atomicAdd(&num[b * 256 + t], sum);
  }
  #undef STAGE
}

// ---------------------------------------------------------------------------
// finish: out = num / den
// ---------------------------------------------------------------------------
__global__ __launch_bounds__(256) void finish_kernel(
    const float* __restrict__ ws_f, float* __restrict__ out)
{
  const int b = blockIdx.x;
  const int t = threadIdx.x;
  out[b * 256 + t] = ws_f[WS_NUM + b * 256 + t] / ws_f[WS_DEN + b];
}

extern "C" void kernel_launch(void* const* d_in, const int* in_sizes, int n_in,
                              void* d_out, int out_size, void* d_ws, size_t ws_size,
                              hipStream_t stream) {
  const float* a  = (const float*)d_in[0];
  const float* s  = (const float*)d_in[1];
  const float* W1 = (const float*)d_in[2];
  const float* b1 = (const float*)d_in[3];
  const float* W2 = (const float*)d_in[4];
  const float* b2 = (const float*)d_in[5];
  float* out = (float*)d_out;
  float* ws  = (float*)d_ws;

  prep_kernel<<<dim3(B_), dim3(256), 0, stream>>>(s, W1, b1, W2, ws);
  fused_kernel<<<dim3(2048), dim3(256), 0, stream>>>(
      a, ws, b2, ws + WS_NUM, ws + WS_DEN);
  finish_kernel<<<dim3(B_), dim3(256), 0, stream>>>(ws, out);
}

// Round 5
// 56.827 us; speedup vs baseline: 6.7691x; 1.1651x over previous
//
#include <hip/hip_runtime.h>

#define B_ 64
#define TX_ 2048
#define DA_ 256
#define DS_ 256
#define H_ 50

typedef __attribute__((ext_vector_type(4))) float f32x4;
typedef __attribute__((ext_vector_type(8))) short short8;

// bf16 RNE helpers
__device__ __forceinline__ unsigned short f2bf(float x) {
  unsigned int u = __builtin_bit_cast(unsigned int, x);
  u += 0x7FFFu + ((u >> 16) & 1u);
  return (unsigned short)(u >> 16);
}
__device__ __forceinline__ float bf2f(unsigned short h) {
  unsigned int u = ((unsigned int)h) << 16;
  return __builtin_bit_cast(float, u);
}

// ws layout (float units): num[16384] @0 | den[64] @16384 | c_ws[64*64] @16448
// | w2p[64] @20544 | wsB (32768 ushort = 64KB) @float 20608
#define WS_NUM 0
#define WS_DEN 16384
#define WS_C   16448
#define WS_W2  20544
#define WS_B   20608

// ---------------------------------------------------------------------------
// prep: zero num/den; c[b][h] = b1[h] + s@W1s (padded to 64); w2 padded;
// W1a split hi/lo into MFMA B-fragment order.
// ---------------------------------------------------------------------------
__global__ __launch_bounds__(256) void prep_kernel(
    const float* __restrict__ s, const float* __restrict__ W1,
    const float* __restrict__ b1, const float* __restrict__ W2,
    float* __restrict__ ws)
{
  const int b = blockIdx.x;
  const int t = threadIdx.x;
  float* num = ws + WS_NUM;
  float* den = ws + WS_DEN;
  float* cws = ws + WS_C;
  float* w2p = ws + WS_W2;
  unsigned short* wsB = (unsigned short*)(ws + WS_B);

  num[b * 256 + t] = 0.0f;
  if (t == 0) den[b] = 0.0f;

  {
    const int h4 = t >> 2, kq = t & 3;
    float cp = 0.0f;
    if (h4 < H_) {
      const float* srow = s + b * DS_;
      #pragma unroll 8
      for (int k = kq * 64; k < kq * 64 + 64; ++k)
        cp += srow[k] * W1[(size_t)(DA_ + k) * H_ + h4];
    }
    cp += __shfl_down(cp, 1);
    cp += __shfl_down(cp, 2);
    if (kq == 0) cws[b * 64 + h4] = (h4 < H_) ? (cp + b1[h4]) : 0.0f;
  }
  if (b == 0 && t < 64) w2p[t] = (t < H_) ? W2[t] : 0.0f;

  #pragma unroll
  for (int ii = 0; ii < 2; ++ii) {
    const int idx = (b * 256 + t) * 2 + ii;
    const int j = idx & 7;
    const int l = (idx >> 3) & 63;
    const int nt = (idx >> 9) & 3;
    const int term = (idx >> 11) & 1;
    const int c = idx >> 12;
    const int k = c * 32 + (l >> 4) * 8 + j;
    const int n = nt * 16 + (l & 15);
    const float wv = (n < H_) ? W1[(size_t)k * H_ + n] : 0.0f;
    const unsigned short hi = f2bf(wv);
    const unsigned short val = term == 0 ? hi : f2bf(wv - bf2f(hi));
    wsB[((size_t)((c * 2 + term) * 4 + nt)) * 512 + l * 8 + j] = val;
  }
}

// ---------------------------------------------------------------------------
// fused: grid 2048 x 256 (4 waves). Block = 64 rows of one batch.
// BARRIER-FREE pass 1: wave w stages rows [16w,16w+16) and only ever reads
// those rows -> per-wave counted vmcnt, no s_barrier until pass 2.
// B-fragments double-buffered in registers, issued one chunk ahead.
// vmcnt: leave newest 10 = {stage[c+2](2), B[c+1](8)}; stage[c] has >=20
// younger ops at the wait -> always retired (robust to compiler interleave).
// ---------------------------------------------------------------------------
__global__ __launch_bounds__(256) void fused_kernel(
    const float* __restrict__ a, const float* __restrict__ ws_f,
    const float* __restrict__ b2, float* __restrict__ num,
    float* __restrict__ den)
{
  __shared__ float tile[16384];  // 64KB: chunk c at floats [c*2048, +2048)
  __shared__ float w_sh[64];

  const int t = threadIdx.x;
  const int l = t & 63;
  const int w = __builtin_amdgcn_readfirstlane(t >> 6);
  const int blk = blockIdx.x;
  const int b = blk >> 5;          // 32 blocks per batch
  const long R0 = (long)blk * 64;  // first global row

  const float* cws = ws_f + WS_C;
  const float* w2p = ws_f + WS_W2;
  const unsigned short* wsB = (const unsigned short*)(ws_f + WS_B);

  // per-thread epilogue constants (no LDS, no barrier needed)
  float cv[4], w2v[4];
  #pragma unroll
  for (int nt = 0; nt < 4; ++nt) {
    const int n = nt * 16 + (l & 15);
    cv[nt] = cws[b * 64 + n];
    w2v[nt] = w2p[n];
  }
  const float b2v = b2[0];

  // Stage chunk c: wave w stages its own rows [16w,16w+16). LDS dest linear;
  // global source pre-swizzled (byte ^ ((row&7)<<4)) for conflict-free reads.
  #define STAGE(c)                                                             \
    {                                                                          \
      _Pragma("unroll")                                                        \
      for (int i = 0; i < 2; ++i) {                                            \
        const int slot = w * 2 + i;                                            \
        const int row = slot * 8 + (l >> 3);                                   \
        const long gbyte = (R0 + row) * 1024 + (c) * 128 +                     \
                           (((l & 7) ^ ((l >> 3) & 7)) * 16);                  \
        __builtin_amdgcn_global_load_lds(                                      \
            (const __attribute__((address_space(1))) void*)((const char*)a +   \
                                                            gbyte),            \
            (__attribute__((address_space(3))) void*)&tile[(c)*2048 +          \
                                                           slot * 256],        \
            16, 0, 0);                                                         \
      }                                                                        \
    }

  STAGE(0);
  STAGE(1);

  // B double-buffer in registers; prologue loads chunk 0 into set 0.
  short8 Bh[2][4], Bl[2][4];
  {
    const short8* Bp = (const short8*)wsB;
    #pragma unroll
    for (int nt = 0; nt < 4; ++nt) {
      Bh[0][nt] = Bp[nt * 64 + l];
      Bl[0][nt] = Bp[(4 + nt) * 64 + l];
    }
  }

  f32x4 acc[4];
  #pragma unroll
  for (int nt = 0; nt < 4; ++nt) acc[nt] = (f32x4){0.f, 0.f, 0.f, 0.f};

  #pragma unroll
  for (int c = 0; c < 8; ++c) {
    if (c + 2 < 8) STAGE(c + 2);
    if (c + 1 < 8) {
      const short8* Bp = (const short8*)(wsB + (size_t)(c + 1) * 4096);
      #pragma unroll
      for (int nt = 0; nt < 4; ++nt) {
        Bh[(c + 1) & 1][nt] = Bp[nt * 64 + l];
        Bl[(c + 1) & 1][nt] = Bp[(4 + nt) * 64 + l];
      }
    }
    // per-wave counted wait: own stage[c] guaranteed retired; no barrier.
    if (c < 6)       asm volatile("s_waitcnt vmcnt(10)" ::: "memory");
    else if (c == 6) asm volatile("s_waitcnt vmcnt(8)" ::: "memory");
    else             asm volatile("s_waitcnt vmcnt(0)" ::: "memory");
    __builtin_amdgcn_sched_barrier(0);

    // A-fragment from this wave's own staged rows
    const int row = w * 16 + (l & 15);
    const int mask = (l & 7) << 4;
    const int obase = (l >> 4) * 32;
    const char* tb = (const char*)tile + (size_t)c * 8192 + row * 128;
    const float4 v0 = *(const float4*)(tb + (obase ^ mask));
    const float4 v1 = *(const float4*)(tb + ((obase + 16) ^ mask));
    float av[8] = {v0.x, v0.y, v0.z, v0.w, v1.x, v1.y, v1.z, v1.w};
    short8 Ah, Al;
    #pragma unroll
    for (int j = 0; j < 8; ++j) {
      const unsigned short hi = f2bf(av[j]);
      Ah[j] = (short)hi;
      Al[j] = (short)f2bf(av[j] - bf2f(hi));
    }

    #pragma unroll
    for (int nt = 0; nt < 4; ++nt) {
      acc[nt] = __builtin_amdgcn_mfma_f32_16x16x32_bf16(Ah, Bh[c & 1][nt], acc[nt], 0, 0, 0);
      acc[nt] = __builtin_amdgcn_mfma_f32_16x16x32_bf16(Ah, Bl[c & 1][nt], acc[nt], 0, 0, 0);
      acc[nt] = __builtin_amdgcn_mfma_f32_16x16x32_bf16(Al, Bh[c & 1][nt], acc[nt], 0, 0, 0);
    }
  }

  // Epilogue: h -> e -> w. C layout: n = nt*16+(l&15), row = w*16+(l>>4)*4+r
  #pragma unroll
  for (int r = 0; r < 4; ++r) {
    float e = 0.0f;
    #pragma unroll
    for (int nt = 0; nt < 4; ++nt)
      e += fmaxf(acc[nt][r] + cv[nt], 0.0f) * w2v[nt];
    e += __shfl_xor(e, 1);
    e += __shfl_xor(e, 2);
    e += __shfl_xor(e, 4);
    e += __shfl_xor(e, 8);
    if ((l & 15) == 0)
      w_sh[w * 16 + (l >> 4) * 4 + r] = __expf(tanhf(e + b2v));
  }
  __syncthreads();  // the only block-wide barrier (w_sh + tile for pass 2)

  // Denominator partial (wave 0)
  if (t < 64) {
    float v = w_sh[t];
    #pragma unroll
    for (int off = 32; off > 0; off >>= 1) v += __shfl_xor(v, off);
    if (t == 0) atomicAdd(&den[b], v);
  }

  // Pass 2: context partials from the LDS tile. Thread t owns column t:
  // chunk = t>>5, col-in-chunk = t&31 (2-way bank aliasing = free).
  {
    const int cc = t >> 5, col = t & 31;
    const char* tb = (const char*)tile + (size_t)cc * 8192;
    float sum = 0.0f;
    #pragma unroll 8
    for (int r = 0; r < 64; ++r) {
      const float av = *(const float*)(tb + r * 128 + ((col * 4) ^ ((r & 7) << 4)));
      sum += w_sh[r] * av;
    }
    atomicAdd(&num[b * 256 + t], sum);
  }
  #undef STAGE
}

// ---------------------------------------------------------------------------
// finish: out = num / den
// ---------------------------------------------------------------------------
__global__ __launch_bounds__(256) void finish_kernel(
    const float* __restrict__ ws_f, float* __restrict__ out)
{
  const int b = blockIdx.x;
  const int t = threadIdx.x;
  out[b * 256 + t] = ws_f[WS_NUM + b * 256 + t] / ws_f[WS_DEN + b];
}

extern "C" void kernel_launch(void* const* d_in, const int* in_sizes, int n_in,
                              void* d_out, int out_size, void* d_ws, size_t ws_size,
                              hipStream_t stream) {
  const float* a  = (const float*)d_in[0];
  const float* s  = (const float*)d_in[1];
  const float* W1 = (const float*)d_in[2];
  const float* b1 = (const float*)d_in[3];
  const float* W2 = (const float*)d_in[4];
  const float* b2 = (const float*)d_in[5];
  float* out = (float*)d_out;
  float* ws  = (float*)d_ws;

  prep_kernel<<<dim3(B_), dim3(256), 0, stream>>>(s, W1, b1, W2, ws);
  fused_kernel<<<dim3(2048), dim3(256), 0, stream>>>(
      a, ws, b2, ws + WS_NUM, ws + WS_DEN);
  finish_kernel<<<dim3(B_), dim3(256), 0, stream>>>(ws, out);
}